// Round 3
// baseline (344.504 us; speedup 1.0000x reference)
//
#include <hip/hip_runtime.h>
#include <hip/hip_bf16.h>

// Capsule routing, restructured to avoid materializing hat (B,C,N,D):
//   b[c,n] = x[n,:]·w~[c,:],  w~[c,k] = sum_d o[c,d] W[k,c*16+d]
//   y[c,k] = sum_n softmax_c(b)[c,n] x[n,k],  o = squash(y[c,:]·W_c)
// 3 passes over x (134 MB) instead of ~3.2 GB of hat traffic.

#define BATCH 128
#define SEQ   2048
#define KDIM  128
#define NCAP  32
#define DCAP  16

typedef __attribute__((ext_vector_type(8))) short bf16x8;
typedef __attribute__((ext_vector_type(4))) float f32x4;

__device__ __forceinline__ short f2bf(float f) {
  unsigned u = __float_as_uint(f);
  u = u + 0x7fffu + ((u >> 16) & 1u);   // round-to-nearest-even
  return (short)(u >> 16);
}

// ---------------- Kernel 1: S[b][k] = sum_n x[b][n][k] ----------------
__global__ void colsum_k(const float* __restrict__ x, float* __restrict__ S) {
  int b  = blockIdx.x >> 3;      // 8 blocks/batch, 256 rows each
  int ch = blockIdx.x & 7;
  int t  = threadIdx.x;          // 256
  int k = t & 127, rh = t >> 7;
  const float* xp = x + ((size_t)b * SEQ + ch * 256 + rh) * KDIM + k;
  float acc = 0.f;
  #pragma unroll 8
  for (int r = 0; r < 256; r += 2) acc += xp[(size_t)r * KDIM];
  __shared__ float red[256];
  red[t] = acc;
  __syncthreads();
  if (t < 128) atomicAdd(&S[b * KDIM + k], red[t] + red[t + 128]);
}

// ---------------- Kernel 2: y -> o (squash) -> w~ (or final out) ------
// mode 0: y_eff = S/32 (uniform c of iter 0) -> w~
// mode 1: y from ws -> w~
// mode 2: y from ws -> write o to d_out
__global__ void route_small_k(const float* __restrict__ W,
                              const float* __restrict__ S,
                              const float* __restrict__ y,
                              short* __restrict__ wt,
                              float* __restrict__ out,
                              int mode) {
  int b = blockIdx.x;
  int t = threadIdx.x;           // 512 = 32 capsules x 16 dims
  int c = t >> 4, d = t & 15;
  float s = 0.f;
  if (mode == 0) {
    const float* Sp = S + b * KDIM;
    #pragma unroll 4
    for (int k = 0; k < KDIM; ++k) s += Sp[k] * W[k * 512 + c * DCAP + d];
    s *= (1.f / 32.f);
  } else {
    const float* yp = y + ((size_t)b * NCAP + c) * KDIM;
    #pragma unroll 4
    for (int k = 0; k < KDIM; ++k) s += yp[k] * W[k * 512 + c * DCAP + d];
  }
  // squash: s2 over the 16 dims of this capsule (16-lane butterfly)
  float s2 = s * s;
  s2 += __shfl_xor(s2, 1);
  s2 += __shfl_xor(s2, 2);
  s2 += __shfl_xor(s2, 4);
  s2 += __shfl_xor(s2, 8);
  s2 += 1e-7f;
  float scale = sqrtf(s2) / (0.5f + s2);
  float o = scale * s;
  if (mode == 2) { out[(size_t)b * 512 + t] = o; return; }
  __shared__ float olds[512];
  olds[t] = o;
  __syncthreads();
  // w~[c,k] = sum_d o[c,d] * W[k, c*16+d]; 4096 entries, 8 per thread
  int kb = t & 15;
  #pragma unroll
  for (int i = 0; i < 8; ++i) {
    int k = kb + i * 16;
    float acc = 0.f;
    #pragma unroll
    for (int dd = 0; dd < DCAP; ++dd)
      acc += olds[c * DCAP + dd] * W[k * 512 + c * DCAP + dd];
    wt[((size_t)b * NCAP + c) * KDIM + k] = f2bf(acc);
  }
}

// ---------------- Kernel 3: one routing pass ---------------------------
// scores = x @ w~^T -> softmax over 32 capsules -> y += cn^T @ x
// 4 blocks per batch (512 rows each), 256 threads, MFMA 16x16x32 bf16.
__global__ __launch_bounds__(256, 2) void pass_k(const float* __restrict__ x,
                                                 const short* __restrict__ wt,
                                                 float* __restrict__ yout) {
  __shared__ char lx[32768];     // 128 rows x 128 k, bf16, XOR-swizzled
  __shared__ char lw[8192];      // w~ 32 x 128, bf16, XOR-swizzled
  __shared__ char lcn[8192];     // cn^T 32 x 128, bf16, XOR-swizzled
  __shared__ float yred[4096];   // cross-wave y reduction

  int b = blockIdx.x >> 2, pb = blockIdx.x & 3;
  int t = threadIdx.x;
  int wv = t >> 6, lane = t & 63, l15 = lane & 15, lg = lane >> 4;

  // stage w~ -> lw (swizzle ^(c&7)<<4 to break 256B-stride conflicts)
  {
    int e = t * 16, c = e >> 7, k = e & 127;
    const short* gw = wt + (size_t)b * 4096 + e;
    bf16x8 w0 = *(const bf16x8*)gw;
    bf16x8 w1 = *(const bf16x8*)(gw + 8);
    int swz = (c & 7) << 4;
    *(bf16x8*)(lw + ((c * 256 + k * 2) ^ swz)) = w0;
    *(bf16x8*)(lw + ((c * 256 + (k + 8) * 2) ^ swz)) = w1;
  }

  f32x4 zz = {0.f, 0.f, 0.f, 0.f};
  f32x4 yacc[2][8];
  #pragma unroll
  for (int i = 0; i < 2; ++i)
    #pragma unroll
    for (int j = 0; j < 8; ++j) yacc[i][j] = zz;

  const size_t xbase = ((size_t)b * SEQ + (size_t)pb * 512) * KDIM;

  for (int chunk = 0; chunk < 4; ++chunk) {
    // ---- stage 128-row x chunk, fp32 -> bf16, swizzled ----
    // 128 rows x 16 octets (8 bf16 = 16B each) = 2048 slots; 256 thr x 8 sub.
    {
      int oct = t & 15, rsub = t >> 4;
      #pragma unroll
      for (int sub = 0; sub < 8; ++sub) {
        int r = sub * 16 + rsub;
        const float* gp = x + xbase + (size_t)(chunk * 128 + r) * KDIM + oct * 8;
        float4 f0 = *(const float4*)gp;
        float4 f1 = *(const float4*)(gp + 4);
        bf16x8 v;
        short* vp = (short*)&v;
        vp[0] = f2bf(f0.x); vp[1] = f2bf(f0.y); vp[2] = f2bf(f0.z); vp[3] = f2bf(f0.w);
        vp[4] = f2bf(f1.x); vp[5] = f2bf(f1.y); vp[6] = f2bf(f1.z); vp[7] = f2bf(f1.w);
        *(bf16x8*)(lx + ((r * 256 + oct * 16) ^ ((r & 7) << 4))) = v;
      }
    }
    __syncthreads();

    // ---- GEMM1: scores, wave wv owns rows [wv*32, wv*32+32) ----
    f32x4 sc[2][2];
    sc[0][0] = zz; sc[0][1] = zz; sc[1][0] = zz; sc[1][1] = zz;
    #pragma unroll
    for (int ks = 0; ks < 4; ++ks) {
      bf16x8 a[2], bw[2];
      #pragma unroll
      for (int mi = 0; mi < 2; ++mi) {
        int row = wv * 32 + mi * 16 + l15;
        a[mi] = *(const bf16x8*)(lx + ((row * 256 + ks * 64 + lg * 16) ^ ((row & 7) << 4)));
      }
      #pragma unroll
      for (int ct = 0; ct < 2; ++ct) {
        int cc = ct * 16 + l15;
        bw[ct] = *(const bf16x8*)(lw + ((cc * 256 + ks * 64 + lg * 16) ^ ((cc & 7) << 4)));
      }
      #pragma unroll
      for (int mi = 0; mi < 2; ++mi)
        #pragma unroll
        for (int ct = 0; ct < 2; ++ct)
          sc[mi][ct] = __builtin_amdgcn_mfma_f32_16x16x32_bf16(a[mi], bw[ct], sc[mi][ct], 0, 0, 0);
    }

    // ---- softmax over 32 capsules per row; write cn^T to lcn ----
    #pragma unroll
    for (int mi = 0; mi < 2; ++mi) {
      #pragma unroll
      for (int r = 0; r < 4; ++r) {
        float v0 = sc[mi][0][r], v1 = sc[mi][1][r];
        float mx = fmaxf(v0, v1);
        mx = fmaxf(mx, __shfl_xor(mx, 1));
        mx = fmaxf(mx, __shfl_xor(mx, 2));
        mx = fmaxf(mx, __shfl_xor(mx, 4));
        mx = fmaxf(mx, __shfl_xor(mx, 8));
        float e0 = __expf(v0 - mx), e1 = __expf(v1 - mx);
        float sm = e0 + e1;
        sm += __shfl_xor(sm, 1);
        sm += __shfl_xor(sm, 2);
        sm += __shfl_xor(sm, 4);
        sm += __shfl_xor(sm, 8);
        float inv = 1.f / sm;
        int row = wv * 32 + mi * 16 + lg * 4 + r;
        int c0 = l15, c1 = 16 + l15;
        *(short*)(lcn + ((c0 * 256 + row * 2) ^ ((c0 & 7) << 4))) = f2bf(e0 * inv);
        *(short*)(lcn + ((c1 * 256 + row * 2) ^ ((c1 & 7) << 4))) = f2bf(e1 * inv);
      }
    }
    __syncthreads();

    // ---- GEMM2: y += cn^T @ x, wave wv contracts rows [wv*32, wv*32+32) ----
    {
      bf16x8 a2[2];
      #pragma unroll
      for (int m2 = 0; m2 < 2; ++m2) {
        int cc = m2 * 16 + l15;
        a2[m2] = *(const bf16x8*)(lcn + ((cc * 256 + wv * 64 + lg * 16) ^ ((cc & 7) << 4)));
      }
      #pragma unroll
      for (int nt = 0; nt < 8; ++nt) {
        bf16x8 bx;
        short* bp = (short*)&bx;
        int col = nt * 16 + l15;
        int rbase = wv * 32 + lg * 8;
        #pragma unroll
        for (int j = 0; j < 8; ++j) {
          int row = rbase + j;   // row&7 == j -> per-j uniform swizzle
          bp[j] = *(const short*)(lx + ((row * 256 + col * 2) ^ ((row & 7) << 4)));
        }
        yacc[0][nt] = __builtin_amdgcn_mfma_f32_16x16x32_bf16(a2[0], bx, yacc[0][nt], 0, 0, 0);
        yacc[1][nt] = __builtin_amdgcn_mfma_f32_16x16x32_bf16(a2[1], bx, yacc[1][nt], 0, 0, 0);
      }
    }
    __syncthreads();
  }

  // ---- reduce the 4 waves' y partials in LDS, then global atomic add ----
  #pragma unroll 1
  for (int round = 0; round < 4; ++round) {
    if (wv == round) {
      #pragma unroll
      for (int m2 = 0; m2 < 2; ++m2)
        #pragma unroll
        for (int nt = 0; nt < 8; ++nt)
          #pragma unroll
          for (int r = 0; r < 4; ++r) {
            int cc = m2 * 16 + lg * 4 + r;   // C/D layout: col=l15, row=lg*4+r
            int kk = nt * 16 + l15;
            if (round == 0) yred[cc * 128 + kk]  = yacc[m2][nt][r];
            else            yred[cc * 128 + kk] += yacc[m2][nt][r];
          }
    }
    __syncthreads();
  }
  #pragma unroll
  for (int i = 0; i < 16; ++i)
    atomicAdd(&yout[(size_t)b * 4096 + i * 256 + t], yred[i * 256 + t]);
}

extern "C" void kernel_launch(void* const* d_in, const int* in_sizes, int n_in,
                              void* d_out, int out_size, void* d_ws, size_t ws_size,
                              hipStream_t stream) {
  const float* x = (const float*)d_in[0];   // (128, 2048, 128) fp32
  const float* W = (const float*)d_in[1];   // (128, 512) fp32
  float* out = (float*)d_out;               // (128, 32, 16) fp32
  char* ws = (char*)d_ws;
  // ws layout: [S 64KB][y1 2MB][y2 2MB][w~ 1MB]  (total ~5.2 MB)
  float* S  = (float*)ws;
  float* y1 = (float*)(ws + 65536);
  float* y2 = (float*)(ws + 65536 + 2097152);
  short* wt = (short*)(ws + 65536 + 2 * 2097152);

  hipMemsetAsync(d_ws, 0, 65536 + 2 * 2097152, stream);  // zero S, y1, y2

  colsum_k<<<dim3(1024), dim3(256), 0, stream>>>(x, S);
  route_small_k<<<dim3(128), dim3(512), 0, stream>>>(W, S, nullptr, wt, nullptr, 0);
  pass_k<<<dim3(512), dim3(256), 0, stream>>>(x, wt, y1);
  route_small_k<<<dim3(128), dim3(512), 0, stream>>>(W, nullptr, y1, wt, nullptr, 1);
  pass_k<<<dim3(512), dim3(256), 0, stream>>>(x, wt, y2);
  route_small_k<<<dim3(128), dim3(512), 0, stream>>>(W, nullptr, y2, nullptr, out, 2);
}

// Round 4
// 299.627 us; speedup vs baseline: 1.1498x; 1.1498x over previous
//
#include <hip/hip_runtime.h>
#include <hip/hip_bf16.h>

// Capsule routing without materializing hat (B,C,N,D):
//   b[c,n] = x[n,:]·w~[c,:],  w~[c,k] = sum_d o[c,d] W[k,c*16+d]
//   y[c,k] = sum_n softmax_c(b)[c,n] x[n,k],  o = squash(y[c,:]·W_c)
// prep converts x->bf16 swizzled once; two MFMA passes read bf16 (L3-resident).

#define SEQ 2048
#define KD  128

typedef __attribute__((ext_vector_type(8))) short bf16x8;
typedef __attribute__((ext_vector_type(4))) float f32x4;

__device__ __forceinline__ short f2bf(float f) {
  unsigned u = __float_as_uint(f);
  u = u + 0x7fffu + ((u >> 16) & 1u);   // RNE
  return (short)(u >> 16);
}
// lx swizzle: rows 8/16/24 apart land in distinct 32B bank-windows (GEMM2 gather 2-way)
__device__ __forceinline__ int swz(int row) {
  return ((row & 7) << 4) ^ ((row & 24) << 2);
}

// ---- prep: x fp32 -> bf16 pre-swizzled 128-row chunks + colsum S (atomic) ----
__global__ __launch_bounds__(256) void prep_k(const float* __restrict__ x,
                                              short* __restrict__ xs,
                                              float* __restrict__ S) {
  int blk = blockIdx.x;                 // 2048 chunks of 128 rows
  int t = threadIdx.x, oct = t & 15, rsub = t >> 4;
  size_t row0 = (size_t)blk * 128;
  char* dst = (char*)xs + (size_t)blk * 32768;
  float sac[8] = {0.f,0.f,0.f,0.f,0.f,0.f,0.f,0.f};
  #pragma unroll
  for (int sub = 0; sub < 8; ++sub) {
    int r = sub * 16 + rsub;
    const float* gp = x + (row0 + r) * KD + oct * 8;
    float4 f0 = *(const float4*)gp, f1 = *(const float4*)(gp + 4);
    bf16x8 v; short* vp = (short*)&v;
    vp[0] = f2bf(f0.x); vp[1] = f2bf(f0.y); vp[2] = f2bf(f0.z); vp[3] = f2bf(f0.w);
    vp[4] = f2bf(f1.x); vp[5] = f2bf(f1.y); vp[6] = f2bf(f1.z); vp[7] = f2bf(f1.w);
    sac[0] += f0.x; sac[1] += f0.y; sac[2] += f0.z; sac[3] += f0.w;
    sac[4] += f1.x; sac[5] += f1.y; sac[6] += f1.z; sac[7] += f1.w;
    *(bf16x8*)(dst + ((r * 256 + oct * 16) ^ swz(r))) = v;
  }
  __shared__ float red[2048];           // [rsub][oct][j]
  float4* rp = (float4*)&red[rsub * 128 + oct * 8];
  rp[0] = make_float4(sac[0], sac[1], sac[2], sac[3]);
  rp[1] = make_float4(sac[4], sac[5], sac[6], sac[7]);
  __syncthreads();
  if (t < 128) {
    float s = 0.f;
    #pragma unroll
    for (int i = 0; i < 16; ++i) s += red[i * 128 + t];
    atomicAdd(&S[(blk >> 4) * KD + t], s);
  }
}

// ---- small: y -> o (squash) -> w~ bf16 (modes 0/1) or final out (mode 2) ----
// grid = 128 b x 32 c, 64 threads.
__global__ __launch_bounds__(64) void small_k(const float* __restrict__ W,
                                              const float* __restrict__ S,
                                              const float* __restrict__ yp,
                                              short* __restrict__ wt,
                                              float* __restrict__ out,
                                              int mode) {
  int b = blockIdx.x >> 5, c = blockIdx.x & 31;
  int l = threadIdx.x, d = l & 15, kg = l >> 4;
  const float* Wc = W + c * 16;         // W[k*512 + c*16 + d]
  float s = 0.f;
  if (mode == 0) {
    const float* Sp = S + b * KD;
    #pragma unroll 8
    for (int i = 0; i < 32; ++i) { int k = kg * 32 + i; s += Sp[k] * Wc[k * 512 + d]; }
    s *= (1.f / 32.f);
  } else {
    const float* y0 = yp + (size_t)b * 4 * 4096 + c * KD;
    #pragma unroll 8
    for (int i = 0; i < 32; ++i) {
      int k = kg * 32 + i;
      float yv = y0[k] + y0[4096 + k] + y0[8192 + k] + y0[12288 + k];
      s += yv * Wc[k * 512 + d];
    }
  }
  s += __shfl_xor(s, 16); s += __shfl_xor(s, 32);   // full sum over k
  float s2 = s * s;                                  // squash over 16 dims
  s2 += __shfl_xor(s2, 1); s2 += __shfl_xor(s2, 2);
  s2 += __shfl_xor(s2, 4); s2 += __shfl_xor(s2, 8);
  s2 += 1e-7f;
  float o = (sqrtf(s2) / (0.5f + s2)) * s;
  if (mode == 2) { if (l < 16) out[(size_t)b * 512 + c * 16 + l] = o; return; }
  __shared__ float olds[16];
  if (l < 16) olds[l] = o;
  __syncthreads();
  #pragma unroll
  for (int h = 0; h < 2; ++h) {
    int k = l + h * 64;
    float acc = 0.f;
    #pragma unroll
    for (int dd = 0; dd < 16; ++dd) acc += olds[dd] * Wc[k * 512 + dd];
    wt[((size_t)b * 32 + c) * KD + k] = f2bf(acc);
  }
}

// ---- pass: scores = x@w~^T -> softmax over 32 -> ypart = cn^T @ x ----
// 4 blocks/batch (512 rows), 256 thr; reads pre-swizzled bf16 chunks.
__global__ __launch_bounds__(256, 2) void pass_k(const short* __restrict__ xs,
                                                 const short* __restrict__ wt,
                                                 float* __restrict__ yout) {
  __shared__ char ldsbuf[49152];
  char* lx  = ldsbuf;                   // 32KB: 128 rows x 256B, swz
  char* lw  = ldsbuf + 32768;           // 8KB:  w~ 32 x 128 bf16
  char* lcn = ldsbuf + 40960;           // 8KB:  cn^T 32 x 128 bf16
  float* yred = (float*)ldsbuf;         // 16KB alias over lx (used after loop)

  int b = blockIdx.x >> 2;
  int t = threadIdx.x;
  int wv = t >> 6, lane = t & 63, l15 = lane & 15, lg = lane >> 4;

  // stage w~ -> lw  (swizzle (c&7)<<4)
  {
    int e = t * 16, c = e >> 7, k = e & 127;
    const short* gw = wt + (size_t)b * 4096 + e;
    bf16x8 w0 = *(const bf16x8*)gw;
    bf16x8 w1 = *(const bf16x8*)(gw + 8);
    int sw = (c & 7) << 4;
    *(bf16x8*)(lw + ((c * 256 + k * 2) ^ sw)) = w0;
    *(bf16x8*)(lw + ((c * 256 + (k + 8) * 2) ^ sw)) = w1;
  }

  f32x4 zz = {0.f, 0.f, 0.f, 0.f};
  f32x4 yacc[2][8];
  #pragma unroll
  for (int i = 0; i < 2; ++i)
    #pragma unroll
    for (int j = 0; j < 8; ++j) yacc[i][j] = zz;

  for (int chunk = 0; chunk < 4; ++chunk) {
    // ---- stage pre-swizzled bf16 chunk: pure 16B copies ----
    {
      const char* gs = (const char*)xs + ((size_t)blockIdx.x * 4 + chunk) * 32768;
      #pragma unroll
      for (int sub = 0; sub < 8; ++sub) {
        int off = sub * 4096 + t * 16;
        *(bf16x8*)(lx + off) = *(const bf16x8*)(gs + off);
      }
    }
    __syncthreads();

    // ---- GEMM1: scores; wave wv owns rows [wv*32, wv*32+32) ----
    f32x4 sc[2][2];
    sc[0][0] = zz; sc[0][1] = zz; sc[1][0] = zz; sc[1][1] = zz;
    #pragma unroll
    for (int ks = 0; ks < 4; ++ks) {
      bf16x8 a[2], bw[2];
      #pragma unroll
      for (int mi = 0; mi < 2; ++mi) {
        int row = wv * 32 + mi * 16 + l15;
        a[mi] = *(const bf16x8*)(lx + ((row * 256 + ks * 64 + lg * 16) ^ swz(row)));
      }
      #pragma unroll
      for (int ct = 0; ct < 2; ++ct) {
        int cc = ct * 16 + l15;
        bw[ct] = *(const bf16x8*)(lw + ((cc * 256 + ks * 64 + lg * 16) ^ ((cc & 7) << 4)));
      }
      #pragma unroll
      for (int mi = 0; mi < 2; ++mi)
        #pragma unroll
        for (int ct = 0; ct < 2; ++ct)
          sc[mi][ct] = __builtin_amdgcn_mfma_f32_16x16x32_bf16(a[mi], bw[ct], sc[mi][ct], 0, 0, 0);
    }

    // ---- softmax over 32 capsules per row; write cn^T to lcn ----
    #pragma unroll
    for (int mi = 0; mi < 2; ++mi) {
      #pragma unroll
      for (int r = 0; r < 4; ++r) {
        float v0 = sc[mi][0][r], v1 = sc[mi][1][r];
        float mx = fmaxf(v0, v1);
        mx = fmaxf(mx, __shfl_xor(mx, 1));
        mx = fmaxf(mx, __shfl_xor(mx, 2));
        mx = fmaxf(mx, __shfl_xor(mx, 4));
        mx = fmaxf(mx, __shfl_xor(mx, 8));
        float e0 = __expf(v0 - mx), e1 = __expf(v1 - mx);
        float sm = e0 + e1;
        sm += __shfl_xor(sm, 1); sm += __shfl_xor(sm, 2);
        sm += __shfl_xor(sm, 4); sm += __shfl_xor(sm, 8);
        float inv = 1.f / sm;
        int row = wv * 32 + mi * 16 + lg * 4 + r;
        int c0 = l15, c1 = 16 + l15;
        *(short*)(lcn + ((c0 * 256 + row * 2) ^ ((c0 & 7) << 4))) = f2bf(e0 * inv);
        *(short*)(lcn + ((c1 * 256 + row * 2) ^ ((c1 & 7) << 4))) = f2bf(e1 * inv);
      }
    }
    __syncthreads();

    // ---- GEMM2: y += cn^T @ x; wave wv contracts rows [wv*32, wv*32+32) ----
    {
      bf16x8 a2[2];
      #pragma unroll
      for (int m2 = 0; m2 < 2; ++m2) {
        int cc = m2 * 16 + l15;
        a2[m2] = *(const bf16x8*)(lcn + ((cc * 256 + wv * 64 + lg * 16) ^ ((cc & 7) << 4)));
      }
      #pragma unroll
      for (int nt = 0; nt < 8; ++nt) {
        bf16x8 bx;
        short* bp = (short*)&bx;
        int col = nt * 16 + l15;
        int rbase = wv * 32 + lg * 8;
        #pragma unroll
        for (int j = 0; j < 8; ++j) {
          int row = rbase + j;
          bp[j] = *(const short*)(lx + ((row * 256 + col * 2) ^ swz(row)));
        }
        yacc[0][nt] = __builtin_amdgcn_mfma_f32_16x16x32_bf16(a2[0], bx, yacc[0][nt], 0, 0, 0);
        yacc[1][nt] = __builtin_amdgcn_mfma_f32_16x16x32_bf16(a2[1], bx, yacc[1][nt], 0, 0, 0);
      }
    }
    __syncthreads();
  }

  // ---- reduce 4 waves' partials in LDS (alias over lx), plain store ----
  #pragma unroll 1
  for (int round = 0; round < 4; ++round) {
    if (wv == round) {
      #pragma unroll
      for (int m2 = 0; m2 < 2; ++m2)
        #pragma unroll
        for (int nt = 0; nt < 8; ++nt)
          #pragma unroll
          for (int r = 0; r < 4; ++r) {
            int cc = m2 * 16 + lg * 4 + r;   // C/D: col=l15, row=lg*4+r
            int kk = nt * 16 + l15;
            if (round == 0) yred[cc * 128 + kk]  = yacc[m2][nt][r];
            else            yred[cc * 128 + kk] += yacc[m2][nt][r];
          }
    }
    __syncthreads();
  }
  float* yo = yout + (size_t)blockIdx.x * 4096;
  #pragma unroll
  for (int i = 0; i < 16; ++i) yo[i * 256 + t] = yred[i * 256 + t];
}

extern "C" void kernel_launch(void* const* d_in, const int* in_sizes, int n_in,
                              void* d_out, int out_size, void* d_ws, size_t ws_size,
                              hipStream_t stream) {
  const float* x = (const float*)d_in[0];   // (128, 2048, 128) fp32
  const float* W = (const float*)d_in[1];   // (128, 512) fp32
  float* out = (float*)d_out;               // (128, 32, 16) fp32
  char* ws = (char*)d_ws;
  // ws: [S 64KB][y1 8MB][y2 8MB][wt 1MB @16MB+64KB][pad][xs 64MB @20MB] ~ 84MB
  float* S  = (float*)ws;
  float* y1 = (float*)(ws + 65536);
  float* y2 = (float*)(ws + 65536 + 8388608);
  short* wt = (short*)(ws + 65536 + 16777216);
  short* xs = (short*)(ws + 20971520);

  hipMemsetAsync(S, 0, 65536, stream);      // zero S only (y uses partials)

  prep_k <<<dim3(2048), dim3(256), 0, stream>>>(x, xs, S);
  small_k<<<dim3(4096), dim3(64), 0, stream>>>(W, S, nullptr, wt, nullptr, 0);
  pass_k <<<dim3(512), dim3(256), 0, stream>>>(xs, wt, y1);
  small_k<<<dim3(4096), dim3(64), 0, stream>>>(W, nullptr, y1, wt, nullptr, 1);
  pass_k <<<dim3(512), dim3(256), 0, stream>>>(xs, wt, y2);
  small_k<<<dim3(4096), dim3(64), 0, stream>>>(W, nullptr, y2, nullptr, out, 2);
}